// Round 3
// baseline (283.810 us; speedup 1.0000x reference)
//
#include <hip/hip_runtime.h>
#include <math.h>

#define COS_EPS 1e-8f

typedef float vfloat4 __attribute__((ext_vector_type(4)));

__device__ __forceinline__ float dot4(vfloat4 a, vfloat4 b) {
    return fmaf(a.x, b.x, fmaf(a.y, b.y, fmaf(a.z, b.z, a.w * b.w)));
}

// ---------------------------------------------------------------------------
// R10: revert R9's sort (regression: sort overhead ~20us, zero main-kernel
// gain -> proto re-reads were already Infinity-Cache hits; HBM traffic was
// already at the ~155MB floor). Keep R8's quarter-wave mapping (16 lanes per
// sample, 4 samples/wave, 4-step butterfly) + nt emb loads + partials.
// NEW: single-dispatch — finalize fused via last-block-done. The workspace
// counter is poisoned 0xAA each call, so we use a MONOTONE MODULAR counter:
// grid=1024 (pow2) => any window of 1024 increments crosses a multiple of
// 1024 exactly once => exactly one block per call finalizes, regardless of
// the counter's starting value. Release/acquire via agent-scope atomics.
// ---------------------------------------------------------------------------
__global__ __launch_bounds__(256) void assignment_loss_kernel(
    const float* __restrict__ emb,      // [B, D]
    const int*   __restrict__ labels,   // [B]
    const float* __restrict__ protos,   // [C, D]
    float*       __restrict__ part,     // [gridDim.x] partial sums
    unsigned*    __restrict__ cnt,      // [1] monotone counter (poison-proof)
    float*       __restrict__ out,      // [1] result
    int B, int D, float invB)
{
    const int lane = threadIdx.x & 63;
    const int grp  = lane >> 4;         // 0..3: which sample in the wave
    const int gl   = lane & 15;         // lane within group
    const int wib  = threadIdx.x >> 6;
    const int wpb  = blockDim.x >> 6;
    const int gw   = blockIdx.x * wpb + wib;
    const int nw   = gridDim.x * wpb;

    float local = 0.0f;

    if (D == 512 && (B % (4 * nw)) == 0) {
        const int iters = B / (4 * nw);     // 4 for B=65536, nw=4096
        int s   = gw * 4 + grp;             // this lane's sample
        int lbl = labels[s];                // 4 distinct dwords per wave

        for (int i = 0; i < iters; ++i) {
            const int s_next   = s + 4 * nw;
            const int lbl_next = (i + 1 < iters) ? labels[s_next] : 0;  // prefetch

            const vfloat4* e = (const vfloat4*)(emb    + (size_t)s   * 512);
            const vfloat4* p = (const vfloat4*)(protos + (size_t)lbl * 512);

            // 16 independent loads: 4 rows x 4KB in flight before any use.
            // emb single-use -> nt (evict-first); protos LLC-resident.
            vfloat4 ev[8], pv[8];
            #pragma unroll
            for (int c = 0; c < 8; ++c) ev[c] = __builtin_nontemporal_load(&e[c * 16 + gl]);
            #pragma unroll
            for (int c = 0; c < 8; ++c) pv[c] = p[c * 16 + gl];

            float dot = 0.f, esq = 0.f, psq = 0.f;
            #pragma unroll
            for (int c = 0; c < 8; ++c) {
                dot += dot4(ev[c], pv[c]);
                esq += dot4(ev[c], ev[c]);
                psq += dot4(pv[c], pv[c]);
            }

            // 4-step butterfly within each 16-lane group (4 samples at once)
            #pragma unroll
            for (int off = 8; off > 0; off >>= 1) {
                dot += __shfl_xor(dot, off, 64);
                esq += __shfl_xor(esq, off, 64);
                psq += __shfl_xor(psq, off, 64);
            }

            if (gl == 0) {
                float en = fmaxf(sqrtf(esq), COS_EPS);  // torch eps semantics
                float pn = fmaxf(sqrtf(psq), COS_EPS);
                local += dot / (en * pn);
            }

            s = s_next; lbl = lbl_next;
        }
    } else {
        // generic fallback: wave-per-sample, any D multiple of 256
        const int nchunks = D >> 8;
        for (int smp = gw; smp < B; smp += nw) {
            const int l = labels[smp];
            const vfloat4* e = (const vfloat4*)(emb    + (size_t)smp * (size_t)D);
            const vfloat4* p = (const vfloat4*)(protos + (size_t)l   * (size_t)D);
            float dot = 0.f, esq = 0.f, psq = 0.f;
            for (int c = 0; c < nchunks; ++c) {
                vfloat4 ev = __builtin_nontemporal_load(&e[c * 64 + lane]);
                vfloat4 pv = p[c * 64 + lane];
                dot += dot4(ev, pv);
                esq += dot4(ev, ev);
                psq += dot4(pv, pv);
            }
            #pragma unroll
            for (int off = 32; off > 0; off >>= 1) {
                dot += __shfl_xor(dot, off, 64);
                esq += __shfl_xor(esq, off, 64);
                psq += __shfl_xor(psq, off, 64);
            }
            if (lane == 0) {
                float en = fmaxf(sqrtf(esq), COS_EPS);
                float pn = fmaxf(sqrtf(psq), COS_EPS);
                local += dot / (en * pn);
            }
        }
    }

    // full-wave butterfly, LDS across waves, one partial per block
    #pragma unroll
    for (int off = 32; off > 0; off >>= 1) local += __shfl_xor(local, off, 64);

    __shared__ float smem[8];
    __shared__ int lastflag;
    if (lane == 0) smem[wib] = local;
    __syncthreads();
    if (threadIdx.x == 0) {
        float bs = 0.0f;
        for (int w = 0; w < wpb; ++w) bs += smem[w];
        // publish partial, then bump the monotone counter (release ordering)
        __hip_atomic_store(&part[blockIdx.x], bs, __ATOMIC_RELEASE,
                           __HIP_MEMORY_SCOPE_AGENT);
        unsigned prev = __hip_atomic_fetch_add(cnt, 1u, __ATOMIC_ACQ_REL,
                                               __HIP_MEMORY_SCOPE_AGENT);
        // grid is a power of two: exactly one block per call crosses a
        // multiple-of-grid boundary, whatever the poisoned start value.
        lastflag = (((prev + 1u) & (gridDim.x - 1u)) == 0u);
    }
    __syncthreads();

    if (lastflag) {
        // last-arriving block: all partials are published (acq_rel chain)
        float s = 0.0f;
        for (unsigned i = threadIdx.x; i < gridDim.x; i += blockDim.x)
            s += __hip_atomic_load(&part[i], __ATOMIC_RELAXED,
                                   __HIP_MEMORY_SCOPE_AGENT);
        #pragma unroll
        for (int off = 32; off > 0; off >>= 1) s += __shfl_xor(s, off, 64);
        if (lane == 0) smem[wib] = s;
        __syncthreads();
        if (threadIdx.x == 0) {
            float t = 0.0f;
            for (int w = 0; w < wpb; ++w) t += smem[w];
            out[0] = 1.0f - t * invB;
        }
    }
}

extern "C" void kernel_launch(void* const* d_in, const int* in_sizes, int n_in,
                              void* d_out, int out_size, void* d_ws, size_t ws_size,
                              hipStream_t stream) {
    const float* emb    = (const float*)d_in[0];   // [B, D] float32
    const int*   labels = (const int*)  d_in[1];   // [B] (int32 on device)
    const float* protos = (const float*)d_in[2];   // [C, D] float32
    float*       out    = (float*)d_out;           // scalar float32

    const int B = in_sizes[1];
    const int D = in_sizes[0] / B;                 // 512

    float*    part = (float*)d_ws;                 // [grid] partials
    unsigned* cnt  = (unsigned*)(part + 1024);     // monotone counter

    const int block = 256;                         // 4 waves/block
    const int grid  = 1024;                        // MUST stay pow2 (counter trick)
    assignment_loss_kernel<<<grid, block, 0, stream>>>(
        emb, labels, protos, part, cnt, out, B, D, 1.0f / (float)B);
}

// Round 4
// 204.832 us; speedup vs baseline: 1.3856x; 1.3856x over previous
//
#include <hip/hip_runtime.h>
#include <math.h>

#define COS_EPS 1e-8f

typedef float vfloat4 __attribute__((ext_vector_type(4)));

__device__ __forceinline__ float dot4(vfloat4 a, vfloat4 b) {
    return fmaf(a.x, b.x, fmaf(a.y, b.y, fmaf(a.z, b.z, a.w * b.w)));
}

// R11 = exact revert to R8 (best verified: 204.8 us).
// Post-mortems that fixed this structure:
//  - R9 sort: +20us (proto re-reads were ALREADY Infinity-Cache hits; no HBM
//    traffic to save; sort dispatches are pure overhead).
//  - R10 single-dispatch fusion: +79us (agent-scope release/acq_rel atomics
//    per block force per-XCD L2 writeback/invalidate -> kernel degrades from
//    ~5.9 TB/s logical to ~1 TB/s). NEVER put agent-scope acq_rel atomics in
//    a hot kernel's epilogue on multi-XCD CDNA.
// Decomposition of the 205us total: 2x78us harness poison fills (fixed)
// + ~45us main kernel (~94% of 6.3 TB/s logical roofline) + ~3us finalize.
__global__ __launch_bounds__(256) void assignment_loss_kernel(
    const float* __restrict__ emb,      // [B, D]
    const int*   __restrict__ labels,   // [B]
    const float* __restrict__ protos,   // [C, D]
    float*       __restrict__ part,     // [gridDim.x] partial sums
    int B, int D)
{
    const int lane = threadIdx.x & 63;
    const int grp  = lane >> 4;         // 0..3: which sample in the wave
    const int gl   = lane & 15;         // lane within group
    const int wib  = threadIdx.x >> 6;
    const int wpb  = blockDim.x >> 6;
    const int gw   = blockIdx.x * wpb + wib;
    const int nw   = gridDim.x * wpb;

    float local = 0.0f;

    if (D == 512 && (B % (4 * nw)) == 0) {
        const int iters = B / (4 * nw);     // 4 for B=65536, nw=4096
        int s   = gw * 4 + grp;             // this lane's sample
        int lbl = labels[s];                // 4 distinct dwords per wave

        for (int i = 0; i < iters; ++i) {
            const int s_next   = s + 4 * nw;
            const int lbl_next = (i + 1 < iters) ? labels[s_next] : 0;  // prefetch

            const vfloat4* e = (const vfloat4*)(emb    + (size_t)s   * 512);
            const vfloat4* p = (const vfloat4*)(protos + (size_t)lbl * 512);

            // 16 independent loads: 4 rows x 4KB in flight before any use.
            // emb is single-use -> nt (evict-first), protos cacheable.
            vfloat4 ev[8], pv[8];
            #pragma unroll
            for (int c = 0; c < 8; ++c) ev[c] = __builtin_nontemporal_load(&e[c * 16 + gl]);
            #pragma unroll
            for (int c = 0; c < 8; ++c) pv[c] = p[c * 16 + gl];

            float dot = 0.f, esq = 0.f, psq = 0.f;
            #pragma unroll
            for (int c = 0; c < 8; ++c) {
                dot += dot4(ev[c], pv[c]);
                esq += dot4(ev[c], ev[c]);
                psq += dot4(pv[c], pv[c]);
            }

            // 4-step butterfly within each 16-lane group (reduces 4 samples at once)
            #pragma unroll
            for (int off = 8; off > 0; off >>= 1) {
                dot += __shfl_xor(dot, off, 64);
                esq += __shfl_xor(esq, off, 64);
                psq += __shfl_xor(psq, off, 64);
            }

            if (gl == 0) {
                float en = fmaxf(sqrtf(esq), COS_EPS);  // torch eps semantics
                float pn = fmaxf(sqrtf(psq), COS_EPS);
                local += dot / (en * pn);
            }

            s = s_next; lbl = lbl_next;
        }
    } else {
        // generic fallback: wave-per-sample, any D multiple of 256
        const int nchunks = D >> 8;
        for (int smp = gw; smp < B; smp += nw) {
            const int l = labels[smp];
            const vfloat4* e = (const vfloat4*)(emb    + (size_t)smp * (size_t)D);
            const vfloat4* p = (const vfloat4*)(protos + (size_t)l   * (size_t)D);
            float dot = 0.f, esq = 0.f, psq = 0.f;
            for (int c = 0; c < nchunks; ++c) {
                vfloat4 ev = __builtin_nontemporal_load(&e[c * 64 + lane]);
                vfloat4 pv = p[c * 64 + lane];
                dot += dot4(ev, pv);
                esq += dot4(ev, ev);
                psq += dot4(pv, pv);
            }
            #pragma unroll
            for (int off = 32; off > 0; off >>= 1) {
                dot += __shfl_xor(dot, off, 64);
                esq += __shfl_xor(esq, off, 64);
                psq += __shfl_xor(psq, off, 64);
            }
            if (lane == 0) {
                float en = fmaxf(sqrtf(esq), COS_EPS);
                float pn = fmaxf(sqrtf(psq), COS_EPS);
                local += dot / (en * pn);
            }
        }
    }

    // local is nonzero on group-leader lanes; full-wave butterfly once,
    // then LDS across waves, one plain store per block (no atomic)
    #pragma unroll
    for (int off = 32; off > 0; off >>= 1) local += __shfl_xor(local, off, 64);

    __shared__ float smem[8];
    if (lane == 0) smem[wib] = local;
    __syncthreads();
    if (threadIdx.x == 0) {
        float bs = 0.0f;
        for (int w = 0; w < wpb; ++w) bs += smem[w];
        part[blockIdx.x] = bs;
    }
}

__global__ __launch_bounds__(256) void assignment_loss_finalize(
    const float* __restrict__ part,
    float*       __restrict__ out,
    int nparts, float invB)
{
    float s = 0.0f;
    for (int i = threadIdx.x; i < nparts; i += 256) s += part[i];
    #pragma unroll
    for (int off = 32; off > 0; off >>= 1) s += __shfl_xor(s, off, 64);

    __shared__ float smem[4];
    const int lane = threadIdx.x & 63;
    const int wib  = threadIdx.x >> 6;
    if (lane == 0) smem[wib] = s;
    __syncthreads();
    if (threadIdx.x == 0) {
        float t = smem[0] + smem[1] + smem[2] + smem[3];
        out[0] = 1.0f - t * invB;
    }
}

extern "C" void kernel_launch(void* const* d_in, const int* in_sizes, int n_in,
                              void* d_out, int out_size, void* d_ws, size_t ws_size,
                              hipStream_t stream) {
    const float* emb    = (const float*)d_in[0];   // [B, D] float32
    const int*   labels = (const int*)  d_in[1];   // [B]
    const float* protos = (const float*)d_in[2];   // [C, D] float32
    float*       out    = (float*)d_out;           // scalar float32
    float*       part   = (float*)d_ws;            // [grid] partials (no memset needed)

    const int B = in_sizes[1];
    const int D = in_sizes[0] / B;                 // 512

    const int block = 256;                         // 4 waves/block
    const int grid  = 1024;                        // 4096 waves; occupancy proven non-binding (R6)
    assignment_loss_kernel<<<grid, block, 0, stream>>>(emb, labels, protos, part, B, D);
    assignment_loss_finalize<<<1, block, 0, stream>>>(part, out, grid, 1.0f / (float)B);
}